// Round 1
// baseline (1410.228 us; speedup 1.0000x reference)
//
#include <hip/hip_runtime.h>

#define NPTS 4096
#define NQ   1024
#define NB   8
#define XTW  36            // LDS row stride (floats): 144B, 16B-aligned, breaks pow2 conflicts

// ---------------------------------------------------------------------------
// Kernel 1: farthest point sampling. 1 block per batch, 256 threads, 16 pts/thread.
// Writes new_xyz (exact copies of selected xyz rows) to d_out[0 .. 8*1024*3).
// ---------------------------------------------------------------------------
__global__ __launch_bounds__(256) void fps_kernel(
    const float* __restrict__ xyz, float* __restrict__ out_newxyz)
{
  const int b    = blockIdx.x;
  const int t    = threadIdx.x;
  const int lane = t & 63;
  const int wave = t >> 6;

  __shared__ float sxyz[NPTS * 3];     // 48 KB
  __shared__ float swd[2][4];
  __shared__ int   swi[2][4];

  const float* xb = xyz + (size_t)b * NPTS * 3;
  for (int i = t; i < NPTS * 3; i += 256) sxyz[i] = xb[i];
  __syncthreads();

  float px[16], py[16], pz[16], dst[16];
#pragma unroll
  for (int k = 0; k < 16; ++k) {
    int p = t + (k << 8);
    px[k] = sxyz[p * 3 + 0];
    py[k] = sxyz[p * 3 + 1];
    pz[k] = sxyz[p * 3 + 2];
    dst[k] = 1e10f;                    // matches reference init 1e10
  }

  int far = 0;                         // reference: farthest starts at 0
  for (int n = 0; n < NQ; ++n) {
    if (t == 0) {
      float* o = out_newxyz + (size_t)(b * NQ + n) * 3;
      o[0] = sxyz[far * 3 + 0];
      o[1] = sxyz[far * 3 + 1];
      o[2] = sxyz[far * 3 + 2];
    }
    const float ccx = sxyz[far * 3 + 0];
    const float ccy = sxyz[far * 3 + 1];
    const float ccz = sxyz[far * 3 + 2];

    float bd = -1.0f; int bi = 0;
#pragma unroll
    for (int k = 0; k < 16; ++k) {
      // EXACT reference order: (dx*dx + dy*dy) + dz*dz, no FMA contraction
      float dx = __fsub_rn(px[k], ccx);
      float dy = __fsub_rn(py[k], ccy);
      float dz = __fsub_rn(pz[k], ccz);
      float d2 = __fadd_rn(__fadd_rn(__fmul_rn(dx, dx), __fmul_rn(dy, dy)),
                           __fmul_rn(dz, dz));
      float dm = fminf(dst[k], d2);
      dst[k] = dm;
      if (dm > bd) { bd = dm; bi = t + (k << 8); }   // strict > keeps lowest index
    }
    // wave argmax (first-max-index tiebreak)
#pragma unroll
    for (int m = 1; m < 64; m <<= 1) {
      float od = __shfl_xor(bd, m, 64);
      int   oi = __shfl_xor(bi, m, 64);
      if (od > bd || (od == bd && oi < bi)) { bd = od; bi = oi; }
    }
    const int par = n & 1;             // double-buffered slots -> 1 barrier/iter
    if (lane == 0) { swd[par][wave] = bd; swi[par][wave] = bi; }
    __syncthreads();
    float rd = swd[par][0]; int ri = swi[par][0];
#pragma unroll
    for (int w = 1; w < 4; ++w) {
      float od = swd[par][w]; int oi = swi[par][w];
      if (od > rd || (od == rd && oi < ri)) { rd = od; ri = oi; }
    }
    far = ri;                          // identical in every thread
  }
}

// ---------------------------------------------------------------------------
// Kernel 2: ball query + gather + 3-layer MLP + maxpool. 1 wave per query.
// ---------------------------------------------------------------------------
__device__ __forceinline__ void fma32(float* __restrict__ acc,
                                      const float4* __restrict__ hp, float w)
{
  float4 h0 = hp[0], h1 = hp[1], h2 = hp[2], h3 = hp[3];
  float4 h4 = hp[4], h5 = hp[5], h6 = hp[6], h7 = hp[7];
  acc[0]  = fmaf(h0.x, w, acc[0]);  acc[1]  = fmaf(h0.y, w, acc[1]);
  acc[2]  = fmaf(h0.z, w, acc[2]);  acc[3]  = fmaf(h0.w, w, acc[3]);
  acc[4]  = fmaf(h1.x, w, acc[4]);  acc[5]  = fmaf(h1.y, w, acc[5]);
  acc[6]  = fmaf(h1.z, w, acc[6]);  acc[7]  = fmaf(h1.w, w, acc[7]);
  acc[8]  = fmaf(h2.x, w, acc[8]);  acc[9]  = fmaf(h2.y, w, acc[9]);
  acc[10] = fmaf(h2.z, w, acc[10]); acc[11] = fmaf(h2.w, w, acc[11]);
  acc[12] = fmaf(h3.x, w, acc[12]); acc[13] = fmaf(h3.y, w, acc[13]);
  acc[14] = fmaf(h3.z, w, acc[14]); acc[15] = fmaf(h3.w, w, acc[15]);
  acc[16] = fmaf(h4.x, w, acc[16]); acc[17] = fmaf(h4.y, w, acc[17]);
  acc[18] = fmaf(h4.z, w, acc[18]); acc[19] = fmaf(h4.w, w, acc[19]);
  acc[20] = fmaf(h5.x, w, acc[20]); acc[21] = fmaf(h5.y, w, acc[21]);
  acc[22] = fmaf(h5.z, w, acc[22]); acc[23] = fmaf(h5.w, w, acc[23]);
  acc[24] = fmaf(h6.x, w, acc[24]); acc[25] = fmaf(h6.y, w, acc[25]);
  acc[26] = fmaf(h6.z, w, acc[26]); acc[27] = fmaf(h6.w, w, acc[27]);
  acc[28] = fmaf(h7.x, w, acc[28]); acc[29] = fmaf(h7.y, w, acc[29]);
  acc[30] = fmaf(h7.z, w, acc[30]); acc[31] = fmaf(h7.w, w, acc[31]);
}

__device__ __forceinline__ void layer_acc(float* __restrict__ acc,
                                          const float* __restrict__ XTb,
                                          const float* __restrict__ wg,
                                          int ldw, int nk, int lane)
{
#pragma unroll
  for (int i = 0; i < 32; ++i) acc[i] = 0.0f;
#pragma unroll 4
  for (int k = 0; k < nk; ++k) {
    float w = wg[k * ldw + lane];                       // coalesced, L1-hot
    fma32(acc, (const float4*)(XTb + k * XTW), w);      // broadcast ds_read_b128
  }
}

__device__ __forceinline__ void store_hrow(const float* __restrict__ acc,
                                           float* __restrict__ row,
                                           float sv, float tv)
{
#pragma unroll
  for (int c = 0; c < 8; ++c) {
    float4 h;
    h.x = fmaxf(fmaf(acc[c * 4 + 0], sv, tv), 0.0f);
    h.y = fmaxf(fmaf(acc[c * 4 + 1], sv, tv), 0.0f);
    h.z = fmaxf(fmaf(acc[c * 4 + 2], sv, tv), 0.0f);
    h.w = fmaxf(fmaf(acc[c * 4 + 3], sv, tv), 0.0f);
    *(float4*)(row + c * 4) = h;
  }
}

__global__ __launch_bounds__(64) void sa_kernel(
    const float* __restrict__ xyz, const float* __restrict__ pts,
    const float* __restrict__ w0, const float* __restrict__ b0,
    const float* __restrict__ g0, const float* __restrict__ be0,
    const float* __restrict__ w1, const float* __restrict__ b1,
    const float* __restrict__ g1, const float* __restrict__ be1,
    const float* __restrict__ w2, const float* __restrict__ b2,
    const float* __restrict__ g2, const float* __restrict__ be2,
    const float* __restrict__ newxyz, float* __restrict__ outp)
{
  __shared__ __align__(16) float XT[67 * XTW];   // X^T, then H1^T, then H2^T (aliased)
  __shared__ int bidx[32];

  const int lane = threadIdx.x;
  // XCD swizzle: blockIdx%8 -> XCD; give each XCD exactly one batch for L2 locality
  const int q = ((blockIdx.x & 7) << 10) | (blockIdx.x >> 3);
  const int b = q >> 10;

  const float cx = newxyz[q * 3 + 0];
  const float cy = newxyz[q * 3 + 1];
  const float cz = newxyz[q * 3 + 2];
  const float* xb = xyz + (size_t)b * NPTS * 3;

  // ---- ball query: first <=32 in-radius indices, ascending ----
  int cnt = 0;
  for (int ch = 0; ch < 64; ++ch) {
    int a = (ch << 6) | lane;
    float pxv = xb[a * 3 + 0], pyv = xb[a * 3 + 1], pzv = xb[a * 3 + 2];
    float dx = __fsub_rn(cx, pxv);
    float dy = __fsub_rn(cy, pyv);
    float dz = __fsub_rn(cz, pzv);
    float d2 = __fadd_rn(__fadd_rn(__fmul_rn(dx, dx), __fmul_rn(dy, dy)),
                         __fmul_rn(dz, dz));
    bool in = d2 < 0.04f;                       // RADIUS^2, exact fp32 compare
    unsigned long long bal = __ballot(in);
    int pos = cnt + (int)__popcll(bal & ((1ull << lane) - 1ull));
    if (in && pos < 32) bidx[pos] = a;
    cnt += (int)__popcll(bal);
    if (cnt >= 32) break;                       // wave-uniform
  }
  if (cnt > 32) cnt = 32;
  int i0 = bidx[0];                             // center itself is always in-radius
  if (lane < 32 && lane >= cnt) bidx[lane] = i0;
  __builtin_amdgcn_wave_barrier();

  // ---- gather into X^T[k][s]: rows 0..63 = point features, 64..66 = rel xyz ----
  const int s  = lane & 31;
  const int kc = lane >> 5;
  const int is = bidx[s];
  const float4* pr4 = (const float4*)(pts + ((size_t)(b * NPTS + is)) * 64 + kc * 32);
  float* xcol = XT + s;
#pragma unroll
  for (int c = 0; c < 8; ++c) {
    float4 v = pr4[c];
    xcol[(kc * 32 + c * 4 + 0) * XTW] = v.x;
    xcol[(kc * 32 + c * 4 + 1) * XTW] = v.y;
    xcol[(kc * 32 + c * 4 + 2) * XTW] = v.z;
    xcol[(kc * 32 + c * 4 + 3) * XTW] = v.w;
  }
  if (kc == 0) {
    float ax = xb[is * 3 + 0], ay = xb[is * 3 + 1], az = xb[is * 3 + 2];
    xcol[64 * XTW] = ax - cx;                   // grouped_xyz = xyz[idx] - new_xyz
    xcol[65 * XTW] = ay - cy;
    xcol[66 * XTW] = az - cz;
  }
  __builtin_amdgcn_wave_barrier();

  const float RSQ = rsqrtf(1.0f + 0.001f);      // 1/sqrt(1+BN_EPS)
  float acc[32];

  // ---- layer 1: 67 -> 64, write H1^T ----
  layer_acc(acc, XT, w0, 64, 67, lane);
  {
    float sv = g0[lane] * RSQ;
    float tv = fmaf(b0[lane], sv, be0[lane]);
    store_hrow(acc, XT + lane * XTW, sv, tv);   // reads fully consumed before overwrite
  }
  __builtin_amdgcn_wave_barrier();

  // ---- layer 2: 64 -> 64, write H2^T ----
  layer_acc(acc, XT, w1, 64, 64, lane);
  {
    float sv = g1[lane] * RSQ;
    float tv = fmaf(b1[lane], sv, be1[lane]);
    store_hrow(acc, XT + lane * XTW, sv, tv);
  }
  __builtin_amdgcn_wave_barrier();

  // ---- layer 3: 64 -> 128 in two passes, fused maxpool over s ----
#pragma unroll
  for (int pass = 0; pass < 2; ++pass) {
    const int fofs = pass << 6;
    layer_acc(acc, XT, w2 + fofs, 128, 64, lane);
    float mx = acc[0], mn = acc[0];
#pragma unroll
    for (int i = 1; i < 32; ++i) { mx = fmaxf(mx, acc[i]); mn = fminf(mn, acc[i]); }
    float sv = g2[fofs + lane] * RSQ;
    float tv = fmaf(b2[fofs + lane], sv, be2[fofs + lane]);
    float m  = (sv >= 0.0f) ? mx : mn;          // max over s commutes with affine+relu
    outp[(size_t)q * 128 + fofs + lane] = fmaxf(fmaf(sv, m, tv), 0.0f);
  }
}

// ---------------------------------------------------------------------------
extern "C" void kernel_launch(void* const* d_in, const int* in_sizes, int n_in,
                              void* d_out, int out_size, void* d_ws, size_t ws_size,
                              hipStream_t stream)
{
  const float* xyz = (const float*)d_in[0];
  const float* pts = (const float*)d_in[1];
  const float* w0  = (const float*)d_in[2];
  const float* b0  = (const float*)d_in[3];
  const float* g0  = (const float*)d_in[4];
  const float* be0 = (const float*)d_in[5];
  const float* w1  = (const float*)d_in[6];
  const float* b1  = (const float*)d_in[7];
  const float* g1  = (const float*)d_in[8];
  const float* be1 = (const float*)d_in[9];
  const float* w2  = (const float*)d_in[10];
  const float* b2  = (const float*)d_in[11];
  const float* g2  = (const float*)d_in[12];
  const float* be2 = (const float*)d_in[13];

  float* out    = (float*)d_out;
  float* newxyz = out;                    // 8*1024*3
  float* newpts = out + NB * NQ * 3;      // 8*1024*128

  hipLaunchKernelGGL(fps_kernel, dim3(NB), dim3(256), 0, stream, xyz, newxyz);
  hipLaunchKernelGGL(sa_kernel, dim3(NB * NQ), dim3(64), 0, stream,
                     xyz, pts, w0, b0, g0, be0, w1, b1, g1, be1,
                     w2, b2, g2, be2, newxyz, newpts);
}

// Round 2
// 879.775 us; speedup vs baseline: 1.6029x; 1.6029x over previous
//
#include <hip/hip_runtime.h>

#define NPTS 4096
#define NQ   1024
#define NB   8
#define XTW  36            // LDS row stride (floats) for sa_kernel

#define FPS_T 512
#define FPS_W (FPS_T / 64)     // 8 waves
#define PPT   (NPTS / FPS_T)   // 8 points per thread

// ---------------------------------------------------------------------------
// u64 sortable key: (float_bits(dist) << 32) | ~idx.
// max(key) == argmax(dist) with lowest-index tie-break (dist >= 0 always).
// ---------------------------------------------------------------------------
__device__ __forceinline__ unsigned long long kmax64(unsigned long long a,
                                                     unsigned long long b) {
  return a > b ? a : b;
}

template <int CTRL, int RM>
__device__ __forceinline__ unsigned long long dpp_max64(unsigned long long k) {
  int lo = (int)(unsigned)(k & 0xffffffffull);
  int hi = (int)(unsigned)(k >> 32);
  int plo = __builtin_amdgcn_update_dpp(lo, lo, CTRL, RM, 0xf, false);
  int phi = __builtin_amdgcn_update_dpp(hi, hi, CTRL, RM, 0xf, false);
  unsigned long long o =
      ((unsigned long long)(unsigned)phi << 32) | (unsigned)plo;
  return kmax64(k, o);
}

// ---------------------------------------------------------------------------
// Kernel 1: farthest point sampling. 1 block/batch, 512 threads, 8 pts/thread.
// DPP-based wave argmax (VALU latency) instead of ds_permute shuffles.
// ---------------------------------------------------------------------------
__global__ __launch_bounds__(FPS_T, 1) void fps_kernel(
    const float* __restrict__ xyz, float* __restrict__ out_newxyz)
{
  const int b    = blockIdx.x;
  const int t    = threadIdx.x;
  const int lane = t & 63;
  const int wave = t >> 6;

  __shared__ __align__(16) float sxyz4[NPTS * 4];            // 64 KB, padded
  __shared__ __align__(16) unsigned long long swk[2][FPS_W]; // dbuf slots

  const float* xb = xyz + (size_t)b * NPTS * 3;
  for (int p = t; p < NPTS; p += FPS_T) {
    sxyz4[p * 4 + 0] = xb[p * 3 + 0];
    sxyz4[p * 4 + 1] = xb[p * 3 + 1];
    sxyz4[p * 4 + 2] = xb[p * 3 + 2];
  }
  __syncthreads();

  float px[PPT], py[PPT], pz[PPT], dst[PPT];
#pragma unroll
  for (int k = 0; k < PPT; ++k) {
    int p = t + (k << 9);
    px[k] = sxyz4[p * 4 + 0];
    py[k] = sxyz4[p * 4 + 1];
    pz[k] = sxyz4[p * 4 + 2];
    dst[k] = 1e10f;                    // matches reference init 1e10
  }

  int far = 0;                         // reference: farthest starts at 0
  for (int n = 0; n < NQ; ++n) {
    const float4 c = *(const float4*)(sxyz4 + far * 4);   // broadcast b128
    if (t == 0) {
      float* o = out_newxyz + (size_t)(b * NQ + n) * 3;
      o[0] = c.x; o[1] = c.y; o[2] = c.z;
    }

    unsigned long long kk[PPT];
#pragma unroll
    for (int k = 0; k < PPT; ++k) {
      // EXACT reference order: (dx*dx + dy*dy) + dz*dz, no FMA contraction
      float dx = __fsub_rn(px[k], c.x);
      float dy = __fsub_rn(py[k], c.y);
      float dz = __fsub_rn(pz[k], c.z);
      float d2 = __fadd_rn(__fadd_rn(__fmul_rn(dx, dx), __fmul_rn(dy, dy)),
                           __fmul_rn(dz, dz));
      float dm = fminf(dst[k], d2);
      dst[k] = dm;
      unsigned ib = ~(unsigned)(t + (k << 9));
      kk[k] = ((unsigned long long)__float_as_uint(dm) << 32) | ib;
    }
    // in-lane tree reduce (depth 3)
    unsigned long long m0 = kmax64(kk[0], kk[1]);
    unsigned long long m1 = kmax64(kk[2], kk[3]);
    unsigned long long m2 = kmax64(kk[4], kk[5]);
    unsigned long long m3 = kmax64(kk[6], kk[7]);
    unsigned long long best = kmax64(kmax64(m0, m1), kmax64(m2, m3));

    // wave reduce via DPP (VALU-speed), result in lane 63
    best = dpp_max64<0x111, 0xf>(best);   // row_shr:1
    best = dpp_max64<0x112, 0xf>(best);   // row_shr:2
    best = dpp_max64<0x114, 0xf>(best);   // row_shr:4
    best = dpp_max64<0x118, 0xf>(best);   // row_shr:8
    best = dpp_max64<0x142, 0xa>(best);   // row_bcast:15 -> rows 1,3
    best = dpp_max64<0x143, 0xc>(best);   // row_bcast:31 -> rows 2,3

    unsigned blo = (unsigned)__builtin_amdgcn_readlane(
        (int)(unsigned)(best & 0xffffffffull), 63);
    unsigned bhi =
        (unsigned)__builtin_amdgcn_readlane((int)(unsigned)(best >> 32), 63);
    unsigned long long wkey = ((unsigned long long)bhi << 32) | blo;

    const int par = n & 1;             // double-buffered slots -> 1 barrier/iter
    if (lane == 0) swk[par][wave] = wkey;
    __syncthreads();

    const ulonglong2* sp = (const ulonglong2*)swk[par];
    ulonglong2 a0 = sp[0], a1 = sp[1], a2 = sp[2], a3 = sp[3];
    unsigned long long r0 = kmax64(kmax64(a0.x, a0.y), kmax64(a1.x, a1.y));
    unsigned long long r1 = kmax64(kmax64(a2.x, a2.y), kmax64(a3.x, a3.y));
    unsigned long long mk = kmax64(r0, r1);
    far = (int)(~(unsigned)mk);        // identical in every thread
  }
}

// ---------------------------------------------------------------------------
// Kernel 2: ball query + gather + 3-layer MLP + maxpool. 1 wave per query.
// (unchanged from round 1 — known correct; next optimization target)
// ---------------------------------------------------------------------------
__device__ __forceinline__ void fma32(float* __restrict__ acc,
                                      const float4* __restrict__ hp, float w)
{
  float4 h0 = hp[0], h1 = hp[1], h2 = hp[2], h3 = hp[3];
  float4 h4 = hp[4], h5 = hp[5], h6 = hp[6], h7 = hp[7];
  acc[0]  = fmaf(h0.x, w, acc[0]);  acc[1]  = fmaf(h0.y, w, acc[1]);
  acc[2]  = fmaf(h0.z, w, acc[2]);  acc[3]  = fmaf(h0.w, w, acc[3]);
  acc[4]  = fmaf(h1.x, w, acc[4]);  acc[5]  = fmaf(h1.y, w, acc[5]);
  acc[6]  = fmaf(h1.z, w, acc[6]);  acc[7]  = fmaf(h1.w, w, acc[7]);
  acc[8]  = fmaf(h2.x, w, acc[8]);  acc[9]  = fmaf(h2.y, w, acc[9]);
  acc[10] = fmaf(h2.z, w, acc[10]); acc[11] = fmaf(h2.w, w, acc[11]);
  acc[12] = fmaf(h3.x, w, acc[12]); acc[13] = fmaf(h3.y, w, acc[13]);
  acc[14] = fmaf(h3.z, w, acc[14]); acc[15] = fmaf(h3.w, w, acc[15]);
  acc[16] = fmaf(h4.x, w, acc[16]); acc[17] = fmaf(h4.y, w, acc[17]);
  acc[18] = fmaf(h4.z, w, acc[18]); acc[19] = fmaf(h4.w, w, acc[19]);
  acc[20] = fmaf(h5.x, w, acc[20]); acc[21] = fmaf(h5.y, w, acc[21]);
  acc[22] = fmaf(h5.z, w, acc[22]); acc[23] = fmaf(h5.w, w, acc[23]);
  acc[24] = fmaf(h6.x, w, acc[24]); acc[25] = fmaf(h6.y, w, acc[25]);
  acc[26] = fmaf(h6.z, w, acc[26]); acc[27] = fmaf(h6.w, w, acc[27]);
  acc[28] = fmaf(h7.x, w, acc[28]); acc[29] = fmaf(h7.y, w, acc[29]);
  acc[30] = fmaf(h7.z, w, acc[30]); acc[31] = fmaf(h7.w, w, acc[31]);
}

__device__ __forceinline__ void layer_acc(float* __restrict__ acc,
                                          const float* __restrict__ XTb,
                                          const float* __restrict__ wg,
                                          int ldw, int nk, int lane)
{
#pragma unroll
  for (int i = 0; i < 32; ++i) acc[i] = 0.0f;
#pragma unroll 4
  for (int k = 0; k < nk; ++k) {
    float w = wg[k * ldw + lane];                       // coalesced, L1-hot
    fma32(acc, (const float4*)(XTb + k * XTW), w);      // broadcast ds_read_b128
  }
}

__device__ __forceinline__ void store_hrow(const float* __restrict__ acc,
                                           float* __restrict__ row,
                                           float sv, float tv)
{
#pragma unroll
  for (int c = 0; c < 8; ++c) {
    float4 h;
    h.x = fmaxf(fmaf(acc[c * 4 + 0], sv, tv), 0.0f);
    h.y = fmaxf(fmaf(acc[c * 4 + 1], sv, tv), 0.0f);
    h.z = fmaxf(fmaf(acc[c * 4 + 2], sv, tv), 0.0f);
    h.w = fmaxf(fmaf(acc[c * 4 + 3], sv, tv), 0.0f);
    *(float4*)(row + c * 4) = h;
  }
}

__global__ __launch_bounds__(64) void sa_kernel(
    const float* __restrict__ xyz, const float* __restrict__ pts,
    const float* __restrict__ w0, const float* __restrict__ b0,
    const float* __restrict__ g0, const float* __restrict__ be0,
    const float* __restrict__ w1, const float* __restrict__ b1,
    const float* __restrict__ g1, const float* __restrict__ be1,
    const float* __restrict__ w2, const float* __restrict__ b2,
    const float* __restrict__ g2, const float* __restrict__ be2,
    const float* __restrict__ newxyz, float* __restrict__ outp)
{
  __shared__ __align__(16) float XT[67 * XTW];   // X^T, then H1^T, H2^T (aliased)
  __shared__ int bidx[32];

  const int lane = threadIdx.x;
  const int q = ((blockIdx.x & 7) << 10) | (blockIdx.x >> 3);
  const int b = q >> 10;

  const float cx = newxyz[q * 3 + 0];
  const float cy = newxyz[q * 3 + 1];
  const float cz = newxyz[q * 3 + 2];
  const float* xb = xyz + (size_t)b * NPTS * 3;

  // ---- ball query: first <=32 in-radius indices, ascending ----
  int cnt = 0;
  for (int ch = 0; ch < 64; ++ch) {
    int a = (ch << 6) | lane;
    float pxv = xb[a * 3 + 0], pyv = xb[a * 3 + 1], pzv = xb[a * 3 + 2];
    float dx = __fsub_rn(cx, pxv);
    float dy = __fsub_rn(cy, pyv);
    float dz = __fsub_rn(cz, pzv);
    float d2 = __fadd_rn(__fadd_rn(__fmul_rn(dx, dx), __fmul_rn(dy, dy)),
                         __fmul_rn(dz, dz));
    bool in = d2 < 0.04f;
    unsigned long long bal = __ballot(in);
    int pos = cnt + (int)__popcll(bal & ((1ull << lane) - 1ull));
    if (in && pos < 32) bidx[pos] = a;
    cnt += (int)__popcll(bal);
    if (cnt >= 32) break;
  }
  if (cnt > 32) cnt = 32;
  int i0 = bidx[0];
  if (lane < 32 && lane >= cnt) bidx[lane] = i0;
  __builtin_amdgcn_wave_barrier();

  // ---- gather into X^T[k][s] ----
  const int s  = lane & 31;
  const int kc = lane >> 5;
  const int is = bidx[s];
  const float4* pr4 = (const float4*)(pts + ((size_t)(b * NPTS + is)) * 64 + kc * 32);
  float* xcol = XT + s;
#pragma unroll
  for (int c = 0; c < 8; ++c) {
    float4 v = pr4[c];
    xcol[(kc * 32 + c * 4 + 0) * XTW] = v.x;
    xcol[(kc * 32 + c * 4 + 1) * XTW] = v.y;
    xcol[(kc * 32 + c * 4 + 2) * XTW] = v.z;
    xcol[(kc * 32 + c * 4 + 3) * XTW] = v.w;
  }
  if (kc == 0) {
    float ax = xb[is * 3 + 0], ay = xb[is * 3 + 1], az = xb[is * 3 + 2];
    xcol[64 * XTW] = ax - cx;
    xcol[65 * XTW] = ay - cy;
    xcol[66 * XTW] = az - cz;
  }
  __builtin_amdgcn_wave_barrier();

  const float RSQ = rsqrtf(1.0f + 0.001f);
  float acc[32];

  layer_acc(acc, XT, w0, 64, 67, lane);
  {
    float sv = g0[lane] * RSQ;
    float tv = fmaf(b0[lane], sv, be0[lane]);
    store_hrow(acc, XT + lane * XTW, sv, tv);
  }
  __builtin_amdgcn_wave_barrier();

  layer_acc(acc, XT, w1, 64, 64, lane);
  {
    float sv = g1[lane] * RSQ;
    float tv = fmaf(b1[lane], sv, be1[lane]);
    store_hrow(acc, XT + lane * XTW, sv, tv);
  }
  __builtin_amdgcn_wave_barrier();

#pragma unroll
  for (int pass = 0; pass < 2; ++pass) {
    const int fofs = pass << 6;
    layer_acc(acc, XT, w2 + fofs, 128, 64, lane);
    float mx = acc[0], mn = acc[0];
#pragma unroll
    for (int i = 1; i < 32; ++i) { mx = fmaxf(mx, acc[i]); mn = fminf(mn, acc[i]); }
    float sv = g2[fofs + lane] * RSQ;
    float tv = fmaf(b2[fofs + lane], sv, be2[fofs + lane]);
    float m  = (sv >= 0.0f) ? mx : mn;
    outp[(size_t)q * 128 + fofs + lane] = fmaxf(fmaf(sv, m, tv), 0.0f);
  }
}

// ---------------------------------------------------------------------------
extern "C" void kernel_launch(void* const* d_in, const int* in_sizes, int n_in,
                              void* d_out, int out_size, void* d_ws, size_t ws_size,
                              hipStream_t stream)
{
  const float* xyz = (const float*)d_in[0];
  const float* pts = (const float*)d_in[1];
  const float* w0  = (const float*)d_in[2];
  const float* b0  = (const float*)d_in[3];
  const float* g0  = (const float*)d_in[4];
  const float* be0 = (const float*)d_in[5];
  const float* w1  = (const float*)d_in[6];
  const float* b1  = (const float*)d_in[7];
  const float* g1  = (const float*)d_in[8];
  const float* be1 = (const float*)d_in[9];
  const float* w2  = (const float*)d_in[10];
  const float* b2  = (const float*)d_in[11];
  const float* g2  = (const float*)d_in[12];
  const float* be2 = (const float*)d_in[13];

  float* out    = (float*)d_out;
  float* newxyz = out;                    // 8*1024*3
  float* newpts = out + NB * NQ * 3;      // 8*1024*128

  hipLaunchKernelGGL(fps_kernel, dim3(NB), dim3(FPS_T), 0, stream, xyz, newxyz);
  hipLaunchKernelGGL(sa_kernel, dim3(NB * NQ), dim3(64), 0, stream,
                     xyz, pts, w0, b0, g0, be0, w1, b1, g1, be1,
                     w2, b2, g2, be2, newxyz, newpts);
}